// Round 9
// baseline (600.323 us; speedup 1.0000x reference)
//
#include <hip/hip_runtime.h>
#include <math.h>

#define NN 50000
#define NE 800000
#define AD 32
#define ED 16
#define HD 64
#define NG 256
#define NTILES (NE / 16)     // 50000 wave-tiles of 16 edges
#define EGRID 1280           // persistent blocks for k_edge
#define TPX (NTILES / 8)     // tiles per XCD chunk
#define GGRID 768            // persistent blocks for k_gru (3 per CU)
#define GTILES (NN / 16)     // 3125 node-tiles
#define PGRID 782            // k_pre blocks
#define SGRID 1024           // k_scatter blocks (8 XCD groups x 128)
#define HGRID 1024           // k_hist blocks
#define EPGRID 1024          // k_eprep blocks
#define NPX (NN / 8)         // 6250 nodes per XCD dst-range

typedef short bf16x8 __attribute__((ext_vector_type(8)));
typedef float f32x4  __attribute__((ext_vector_type(4)));
union U4B { uint4 u; bf16x8 v; };

__device__ __forceinline__ float blo(unsigned u){ return __uint_as_float(u << 16); }
__device__ __forceinline__ float bhi(unsigned u){ return __uint_as_float(u & 0xffff0000u); }
__device__ __forceinline__ unsigned short f2bf(float f){
  unsigned u = __float_as_uint(f);
  u += 0x7fffu + ((u >> 16) & 1u);          // RNE
  return (unsigned short)(u >> 16);
}
__device__ __forceinline__ unsigned packbf2(float a, float b){
  return (unsigned)f2bf(a) | ((unsigned)f2bf(b) << 16);
}
__device__ __forceinline__ bf16x8 ldfrag_g(const unsigned* p){
  U4B x; x.u = *(const uint4*)p; return x.v;
}
// relu(a+b+c) on packed bf16 pairs -> packed bf16
__device__ __forceinline__ unsigned srp1(unsigned a, unsigned b, unsigned c){
  float lo = fmaxf(blo(a) + blo(b) + blo(c), 0.f);
  float hi = fmaxf(bhi(a) + bhi(b) + bhi(c), 0.f);
  return packbf2(lo, hi);
}
__device__ __forceinline__ bf16x8 srp4(uint4 a, uint4 b, uint4 c){
  U4B r;
  r.u.x = srp1(a.x, b.x, c.x);
  r.u.y = srp1(a.y, b.y, c.y);
  r.u.z = srp1(a.z, b.z, c.z);
  r.u.w = srp1(a.w, b.w, c.w);
  return r.v;
}

// =============== one-time prep: weights -> bf16 ===============
__global__ __launch_bounds__(256) void k_prep(const float* __restrict__ W1,
                                              const float* __restrict__ W2,
                                              const float* __restrict__ Wih,
                                              const float* __restrict__ Whh,
                                              const float* __restrict__ b1,
                                              unsigned short* __restrict__ W1Tp,
                                              unsigned short* __restrict__ W2Tp,
                                              unsigned short* __restrict__ Wgru,
                                              unsigned short* __restrict__ W1cTp)
{
  int idx = blockIdx.x * 256 + threadIdx.x;
  if (idx < 64 * 168){
    int n = idx / 168, k = idx % 168;
    W1Tp[idx] = (k < 144) ? f2bf(W1[k * 64 + n]) : (unsigned short)0;
    return;
  }
  idx -= 64 * 168;
  if (idx < 64 * 72){
    int n = idx / 72, k = idx % 72;
    W2Tp[idx] = (k < 64) ? f2bf(W2[k * 64 + n]) : (unsigned short)0;
    return;
  }
  idx -= 64 * 72;
  if (idx < 384 * 64){
    int j = idx & 7;
    int g = (idx >> 3) % 384;
    int blk = idx >> 3; blk /= 384;         // 0..7
    int q = blk & 3, ks = blk >> 2;
    int k = ks * 32 + q * 8 + j;
    float v = (g < 192) ? Wih[g * 64 + k] : Whh[(g - 192) * 64 + k];
    Wgru[idx] = f2bf(v);
    return;
  }
  idx -= 384 * 64;
  if (idx < 64 * 32){
    int n = idx / 32, k = idx % 32;
    float v = (k < 16) ? W1[(128 + k) * 64 + n] : (k == 16 ? b1[n] : 0.f);
    W1cTp[idx] = f2bf(v);
  }
}

// =============== CSR build (XCD-partitioned atomics) ===============
__global__ __launch_bounds__(256) void k_hist(const int* __restrict__ eidx, int* __restrict__ deg)
{
  const int g = blockIdx.x & 7, bi = blockIdx.x >> 3;
  const int lo = g * NPX, hi = lo + NPX;
  for (int e = bi * 256 + threadIdx.x; e < NE; e += (HGRID / 8) * 256){
    int d = eidx[NE + e];
    if (d >= lo && d < hi) atomicAdd(&deg[d], 1);
  }
}

__global__ __launch_bounds__(1024) void k_scan1(const int* __restrict__ deg,
                                                int* __restrict__ cur,
                                                int* __restrict__ bsum)
{
  __shared__ int s[1024];
  const int t = threadIdx.x;
  const int idx = blockIdx.x * 1024 + t;
  int v = (idx < NN) ? deg[idx] : 0;
  s[t] = v;
  __syncthreads();
  for (int d = 1; d < 1024; d <<= 1){
    int y = (t >= d) ? s[t - d] : 0;
    __syncthreads();
    s[t] += y;
    __syncthreads();
  }
  if (idx < NN) cur[idx] = s[t] - v;
  if (t == 1023) bsum[blockIdx.x] = s[1023];
}

__global__ __launch_bounds__(64) void k_scan2(const int* __restrict__ bsum,
                                              int* __restrict__ bpre)
{
  const int t = threadIdx.x;
  const int nb = (NN + 1023) / 1024;
  int v = (t < nb) ? bsum[t] : 0;
  int orig = v;
  #pragma unroll
  for (int off = 1; off < 64; off <<= 1){
    int u = __shfl_up(v, off);
    if (t >= off) v += u;
  }
  if (t < nb) bpre[t] = v - orig;
}

__global__ __launch_bounds__(1024) void k_scan3(int* __restrict__ cur,
                                                const int* __restrict__ bpre)
{
  const int idx = blockIdx.x * 1024 + threadIdx.x;
  if (idx < NN) cur[idx] += bpre[blockIdx.x];
}

// scatter: XCD-partitioned — group g only handles dst in its 1/8 range,
// so cur[] atomics and sde[] line writes stay XCD-local and merge in L2.
__global__ __launch_bounds__(256) void k_scatter(const int* __restrict__ eidx,
                                                 int* __restrict__ cur,
                                                 int4* __restrict__ sde)
{
  const int g = blockIdx.x & 7, bi = blockIdx.x >> 3;
  const int lo = g * NPX, hi = lo + NPX;
  for (int e = bi * 256 + threadIdx.x; e < NE; e += (SGRID / 8) * 256){
    int d = eidx[NE + e];
    if (d >= lo && d < hi){
      int s = eidx[e];
      int p = atomicAdd(&cur[d], 1);
      sde[p] = make_int4(s, d, e, 0);
    }
  }
}

// =============== once: E1s[p] = eattr[e(p)]@W1c + b1 in SORTED order + sd8 ===============
__global__ __launch_bounds__(256) void k_eprep(const int4* __restrict__ sde,
                                               const float* __restrict__ eattr,
                                               const unsigned* __restrict__ W1cTp32,
                                               unsigned* __restrict__ E1s,
                                               int2* __restrict__ sd8)
{
  const int t = threadIdx.x, lane = t & 63, wv = t >> 6;
  const int m = lane & 15, q = lane >> 4;
  bf16x8 wf[4];
  #pragma unroll
  for (int tl = 0; tl < 4; ++tl)
    wf[tl] = ldfrag_g(W1cTp32 + (tl * 16 + m) * 16 + q * 4);

  for (int wt = blockIdx.x * 4 + wv; wt < NTILES; wt += EPGRID * 4){
    const int base = wt * 16;
    int4 rec = sde[base + m];
    if (q == 0) sd8[base + m] = make_int2(rec.x, rec.y);
    U4B x;
    if (q < 2){
      const float* ea = eattr + (size_t)rec.z * 16 + q * 8;
      float4 v0 = *(const float4*)(ea);
      float4 v1 = *(const float4*)(ea + 4);
      x.u.x = packbf2(v0.x, v0.y); x.u.y = packbf2(v0.z, v0.w);
      x.u.z = packbf2(v1.x, v1.y); x.u.w = packbf2(v1.z, v1.w);
    } else if (q == 2) x.u = make_uint4(0x3F80u, 0, 0, 0);   // k=16 -> 1.0 (bias slot)
    else               x.u = make_uint4(0, 0, 0, 0);
    bf16x8 a = x.v;
    f32x4 c[4];
    #pragma unroll
    for (int tl = 0; tl < 4; ++tl) c[tl] = f32x4{0.f,0.f,0.f,0.f};
    #pragma unroll
    for (int tl = 0; tl < 4; ++tl)
      c[tl] = __builtin_amdgcn_mfma_f32_16x16x32_bf16(a, wf[tl], c[tl], 0, 0, 0);
    #pragma unroll
    for (int tl = 0; tl < 4; ++tl){
      #pragma unroll
      for (int rr = 0; rr < 4; ++rr){
        float v = c[tl][rr];
        float pp = __shfl_xor(v, 1);
        if (!(m & 1))
          E1s[(size_t)(base + q * 4 + rr) * 32 + (tl * 16 + m) / 2] = packbf2(v, pp);
      }
    }
  }
}

// =============== per step: C12[node] = [h@W1a | h@W1b] bf16 ===============
__global__ __launch_bounds__(256, 4) void k_pre(const unsigned* __restrict__ h_bf,
                                                const unsigned short* __restrict__ W1Tp,
                                                unsigned* __restrict__ C12)
{
  const int t = threadIdx.x, lane = t & 63, wv = t >> 6;
  const int m = lane & 15, q = lane >> 4;
  bf16x8 wa[4][2], wb[4][2];
  #pragma unroll
  for (int tl = 0; tl < 4; ++tl)
    #pragma unroll
    for (int ks = 0; ks < 2; ++ks){
      wa[tl][ks] = ldfrag_g((const unsigned*)(W1Tp + (tl * 16 + m) * 168 + ks * 32 + q * 8));
      wb[tl][ks] = ldfrag_g((const unsigned*)(W1Tp + (tl * 16 + m) * 168 + 64 + ks * 32 + q * 8));
    }
  for (int wt = blockIdx.x * 4 + wv; wt < GTILES; wt += PGRID * 4){
    const int n0 = wt * 16;
    bf16x8 aH[2];
    #pragma unroll
    for (int ks = 0; ks < 2; ++ks)
      aH[ks] = ldfrag_g(h_bf + (size_t)(n0 + m) * 32 + ks * 16 + q * 4);
    f32x4 ca[4], cb[4];
    #pragma unroll
    for (int tl = 0; tl < 4; ++tl){ ca[tl] = f32x4{0.f,0.f,0.f,0.f}; cb[tl] = ca[tl]; }
    #pragma unroll
    for (int ks = 0; ks < 2; ++ks)
      #pragma unroll
      for (int tl = 0; tl < 4; ++tl){
        ca[tl] = __builtin_amdgcn_mfma_f32_16x16x32_bf16(aH[ks], wa[tl][ks], ca[tl], 0, 0, 0);
        cb[tl] = __builtin_amdgcn_mfma_f32_16x16x32_bf16(aH[ks], wb[tl][ks], cb[tl], 0, 0, 0);
      }
    #pragma unroll
    for (int tl = 0; tl < 4; ++tl){
      #pragma unroll
      for (int rr = 0; rr < 4; ++rr){
        const int node = n0 + q * 4 + rr;
        float va = ca[tl][rr], vb = cb[tl][rr];
        float pa = __shfl_xor(va, 1), pb = __shfl_xor(vb, 1);
        if (!(m & 1)){
          C12[(size_t)node * 64 + (tl * 16 + m) / 2]      = packbf2(va, pa);
          C12[(size_t)node * 64 + 32 + (tl * 16 + m) / 2] = packbf2(vb, pb);
        }
      }
    }
  }
}

// =============== embed: h + h_bf (+ zero agg) ===============
__global__ __launch_bounds__(256) void k_embed(const float* __restrict__ x,
                                               const float* __restrict__ We,
                                               const float* __restrict__ be,
                                               float* __restrict__ h,
                                               unsigned* __restrict__ h_bf,
                                               float* __restrict__ agg)
{
  const int t = threadIdx.x;
  const int j = t & 63, nd = t >> 6;
  const int node = blockIdx.x * 4 + nd;
  const float* xr = x + (size_t)node * AD;
  float acc = be[j];
  #pragma unroll 8
  for (int k = 0; k < AD; ++k)
    acc += xr[k] * We[k * HD + j];
  h[(size_t)node * HD + j] = acc;
  agg[(size_t)node * HD + j] = 0.f;
  float p = __shfl_down(acc, 1);
  if (!(j & 1)) h_bf[(size_t)node * 32 + (j >> 1)] = packbf2(acc, p);
}

// =============== edge kernel: no LDS, 8 MFMAs/tile, streaming E1s/sd8 ===============
__global__ __launch_bounds__(256, 4) void k_edge(const unsigned* __restrict__ C12,
                                                 const unsigned* __restrict__ E1s,
                                                 const int2* __restrict__ sd8,
                                                 const unsigned* __restrict__ W2Tp32,
                                                 const float* __restrict__ b2,
                                                 float* __restrict__ agg)
{
  const int t = threadIdx.x;
  const int lane = t & 63, wv = t >> 6;
  const int m = lane & 15, q = lane >> 4;

  bf16x8 w2f[4][2];
  #pragma unroll
  for (int tl = 0; tl < 4; ++tl)
    #pragma unroll
    for (int ks = 0; ks < 2; ++ks)
      w2f[tl][ks] = ldfrag_g(W2Tp32 + (tl * 16 + m) * 36 + ks * 16 + q * 4);

  float b2v[4];
  #pragma unroll
  for (int tl = 0; tl < 4; ++tl) b2v[tl] = b2[tl * 16 + m];

  const int xcd = blockIdx.x & 7, bi = blockIdx.x >> 3;
  const int wend = (xcd + 1) * TPX;
  const int wstep = (EGRID / 8) * 4;
  int wt = xcd * TPX + bi * 4 + wv;

  int2 cursd = sd8[wt * 16 + m];

  while (wt < wend){
    const int wn = wt + wstep;
    const bool hasn = (wn < wend);
    int2 nsd = make_int2(0, 0);
    if (hasn) nsd = sd8[wn * 16 + m];

    const int scur = cursd.x, dcur = cursd.y;

    // gather operands (C1[src], C2[dst]) + stream E1s
    const unsigned* c1p = C12 + (size_t)scur * 64;
    const unsigned* c2p = C12 + (size_t)dcur * 64 + 32;
    const unsigned* e1p = E1s + (size_t)(wt * 16 + m) * 32;
    uint4 c1a = *(const uint4*)(c1p + q * 4);
    uint4 c1b = *(const uint4*)(c1p + 16 + q * 4);
    uint4 c2a = *(const uint4*)(c2p + q * 4);
    uint4 c2b = *(const uint4*)(c2p + 16 + q * 4);
    uint4 e1a = *(const uint4*)(e1p + q * 4);
    uint4 e1b = *(const uint4*)(e1p + 16 + q * 4);

    // hidden = relu(C1+C2+E1) -> bf16 A-frags
    bf16x8 af0 = srp4(c1a, c2a, e1a);
    bf16x8 af1 = srp4(c1b, c2b, e1b);

    // GEMM2: out = hidden @ W2
    f32x4 o0 = {0.f,0.f,0.f,0.f}, o1 = o0, o2 = o0, o3 = o0;
    o0 = __builtin_amdgcn_mfma_f32_16x16x32_bf16(af0, w2f[0][0], o0, 0, 0, 0);
    o1 = __builtin_amdgcn_mfma_f32_16x16x32_bf16(af0, w2f[1][0], o1, 0, 0, 0);
    o2 = __builtin_amdgcn_mfma_f32_16x16x32_bf16(af0, w2f[2][0], o2, 0, 0, 0);
    o3 = __builtin_amdgcn_mfma_f32_16x16x32_bf16(af0, w2f[3][0], o3, 0, 0, 0);
    o0 = __builtin_amdgcn_mfma_f32_16x16x32_bf16(af1, w2f[0][1], o0, 0, 0, 0);
    o1 = __builtin_amdgcn_mfma_f32_16x16x32_bf16(af1, w2f[1][1], o1, 0, 0, 0);
    o2 = __builtin_amdgcn_mfma_f32_16x16x32_bf16(af1, w2f[2][1], o2, 0, 0, 0);
    o3 = __builtin_amdgcn_mfma_f32_16x16x32_bf16(af1, w2f[3][1], o3, 0, 0, 0);

    // segment reduce from C-frags (row=edge q*4+rr, col=tl*16+m)
    int prev = __shfl_up(dcur, 1);
    bool isStart = (m == 0) || (dcur != prev);
    unsigned long long bal = __ballot(isStart);
    unsigned bs = (unsigned)bal & 0xFFFFu;
    int nr = __popc(bs);
    unsigned rem = bs & (bs - 1);
    int lo = 0;
    for (int r = 0; r < nr; ++r){
      int hi = rem ? (__ffs(rem) - 1) : 16;
      rem &= rem - 1;
      float s0 = 0.f, s1 = 0.f, s2 = 0.f, s3 = 0.f;
      #pragma unroll
      for (int rr = 0; rr < 4; ++rr){
        int row = q * 4 + rr;
        bool in = (row >= lo) && (row < hi);
        s0 += in ? o0[rr] : 0.f;
        s1 += in ? o1[rr] : 0.f;
        s2 += in ? o2[rr] : 0.f;
        s3 += in ? o3[rr] : 0.f;
      }
      s0 += __shfl_xor(s0, 16); s0 += __shfl_xor(s0, 32);
      s1 += __shfl_xor(s1, 16); s1 += __shfl_xor(s1, 32);
      s2 += __shfl_xor(s2, 16); s2 += __shfl_xor(s2, 32);
      s3 += __shfl_xor(s3, 16); s3 += __shfl_xor(s3, 32);
      int d = __shfl(dcur, lo);
      float cntf = (float)(hi - lo);
      if (q == 0){
        float v0 = s0 + cntf * b2v[0];
        float v1 = s1 + cntf * b2v[1];
        float v2 = s2 + cntf * b2v[2];
        float v3 = s3 + cntf * b2v[3];
        float* dp = &agg[(size_t)d * HD + m];
        if (r == 0 || r == nr - 1){
          atomicAdd(dp +  0, v0); atomicAdd(dp + 16, v1);
          atomicAdd(dp + 32, v2); atomicAdd(dp + 48, v3);
        } else {
          dp[ 0] = v0; dp[16] = v1; dp[32] = v2; dp[48] = v3;
        }
      }
      lo = hi;
    }

    wt = wn; cursd = nsd;
  }
}

// =============== GRU via MFMA (zeroes agg after consuming it) ===============
__global__ __launch_bounds__(256) void k_gru(float* __restrict__ agg,
                                             float* __restrict__ h,
                                             unsigned* __restrict__ h_bf,
                                             const unsigned short* __restrict__ Wgru,
                                             const float* __restrict__ bih,
                                             const float* __restrict__ bhh)
{
  __shared__ __align__(16) unsigned short sWg[384 * 64];   // 48 KB

  const int t = threadIdx.x;
  {
    const uint4* srcp = (const uint4*)Wgru;
    uint4* dstp = (uint4*)sWg;
    for (int i = t; i < 384 * 64 * 2 / 16; i += 256) dstp[i] = srcp[i];
  }
  __syncthreads();

  const int lane = t & 63, wv = t >> 6;
  const int m = lane & 15, q = lane >> 4;

  float bi_r[4], bi_z[4], bi_n[4], bh_r[4], bh_z[4], bh_n[4];
  #pragma unroll
  for (int tl = 0; tl < 4; ++tl){
    bi_r[tl] = bih[tl * 16 + m];  bi_z[tl] = bih[64 + tl * 16 + m];  bi_n[tl] = bih[128 + tl * 16 + m];
    bh_r[tl] = bhh[tl * 16 + m];  bh_z[tl] = bhh[64 + tl * 16 + m];  bh_n[tl] = bhh[128 + tl * 16 + m];
  }

  for (int wt = blockIdx.x * 4 + wv; wt < GTILES; wt += GGRID * 4){
    const int n0 = wt * 16;

    bf16x8 aA[2], aH[2];
    #pragma unroll
    for (int ks = 0; ks < 2; ++ks){
      const float* ap = agg + (size_t)(n0 + m) * 64 + ks * 32 + q * 8;
      float4 v0 = *(const float4*)ap;
      float4 v1 = *(const float4*)(ap + 4);
      U4B x;
      x.u.x = packbf2(v0.x, v0.y); x.u.y = packbf2(v0.z, v0.w);
      x.u.z = packbf2(v1.x, v1.y); x.u.w = packbf2(v1.z, v1.w);
      aA[ks] = x.v;
      aH[ks] = ldfrag_g(h_bf + (size_t)(n0 + m) * 32 + ks * 16 + q * 4);
    }

    f32x4 ci[12], ch[12];
    #pragma unroll
    for (int tl = 0; tl < 12; ++tl){ ci[tl] = f32x4{0.f,0.f,0.f,0.f}; ch[tl] = ci[tl]; }
    #pragma unroll
    for (int ks = 0; ks < 2; ++ks){
      #pragma unroll
      for (int tl = 0; tl < 12; ++tl){
        bf16x8 bi = *(const bf16x8*)&sWg[((ks * 4 + q) * 384 + tl * 16 + m) * 8];
        ci[tl] = __builtin_amdgcn_mfma_f32_16x16x32_bf16(aA[ks], bi, ci[tl], 0, 0, 0);
        bf16x8 bh = *(const bf16x8*)&sWg[((ks * 4 + q) * 384 + 192 + tl * 16 + m) * 8];
        ch[tl] = __builtin_amdgcn_mfma_f32_16x16x32_bf16(aH[ks], bh, ch[tl], 0, 0, 0);
      }
    }

    #pragma unroll
    for (int tl = 0; tl < 4; ++tl){
      #pragma unroll
      for (int rr = 0; rr < 4; ++rr){
        const int node = n0 + q * 4 + rr;
        float ir = ci[tl][rr]     + bi_r[tl], hr = ch[tl][rr]     + bh_r[tl];
        float iz = ci[4 + tl][rr] + bi_z[tl], hz = ch[4 + tl][rr] + bh_z[tl];
        float in_ = ci[8 + tl][rr] + bi_n[tl], hn = ch[8 + tl][rr] + bh_n[tl];
        float rg = 1.f / (1.f + __expf(-(ir + hr)));
        float zg = 1.f / (1.f + __expf(-(iz + hz)));
        float ng = tanhf(in_ + rg * hn);
        float hold = h[(size_t)node * HD + tl * 16 + m];
        float hnew = (1.f - zg) * ng + zg * hold;
        h[(size_t)node * HD + tl * 16 + m] = hnew;
        agg[(size_t)node * HD + tl * 16 + m] = 0.f;   // re-zero for next step
        float pp = __shfl_xor(hnew, 1);
        if (!(m & 1))
          h_bf[(size_t)node * 32 + tl * 8 + (m >> 1)] = packbf2(hnew, pp);
      }
    }
  }
}

// =============== pool ===============
__global__ __launch_bounds__(256) void k_pool(const float* __restrict__ h,
                                              const int* __restrict__ batch,
                                              float* __restrict__ gsum,
                                              float* __restrict__ cnt)
{
  const int t = threadIdx.x;
  const int j = t & 63, r = t >> 6;
  const int n0 = blockIdx.x * 64 + r * 16;
  float acc = 0.f, c = 0.f;
  int cur = -1;
  for (int i = 0; i < 16; ++i){
    int n = n0 + i;
    if (n >= NN) break;
    int g = batch[n];
    if (g != cur){
      if (cur >= 0){
        atomicAdd(&gsum[cur * HD + j], acc);
        if (j == 0) atomicAdd(&cnt[cur], c);
      }
      cur = g; acc = 0.f; c = 0.f;
    }
    acc += h[(size_t)n * HD + j];
    c += 1.f;
  }
  if (cur >= 0){
    atomicAdd(&gsum[cur * HD + j], acc);
    if (j == 0) atomicAdd(&cnt[cur], c);
  }
}

// =============== head ===============
__global__ __launch_bounds__(64) void k_head(const float* __restrict__ gsum,
                                             const float* __restrict__ cnt,
                                             const float* __restrict__ W1,
                                             const float* __restrict__ b1,
                                             const float* __restrict__ W2,
                                             const float* __restrict__ b2,
                                             float* __restrict__ out)
{
  __shared__ float gv[128];
  const int g = blockIdx.x, j = threadIdx.x;
  float s = gsum[g * HD + j];
  float c = cnt[g];
  gv[j] = s;
  gv[64 + j] = s / fmaxf(c, 1.f);
  __syncthreads();
  float acc = b1[j];
  #pragma unroll 8
  for (int k = 0; k < 128; ++k)
    acc += gv[k] * W1[k * HD + j];
  acc = fmaxf(acc, 0.f);
  float v = acc * W2[j];
  #pragma unroll
  for (int off = 32; off; off >>= 1) v += __shfl_down(v, off, 64);
  if (j == 0) out[g] = v + b2[0];
}

extern "C" void kernel_launch(void* const* d_in, const int* in_sizes, int n_in,
                              void* d_out, int out_size, void* d_ws, size_t ws_size,
                              hipStream_t stream)
{
  (void)in_sizes; (void)n_in; (void)out_size; (void)ws_size;
  const float* x     = (const float*)d_in[0];
  const int*   eidx  = (const int*)d_in[1];
  const float* eattr = (const float*)d_in[2];
  const int*   batch = (const int*)d_in[3];
  const float* We    = (const float*)d_in[4];
  const float* be    = (const float*)d_in[5];
  const float* Wm1   = (const float*)d_in[6];
  const float* bm1   = (const float*)d_in[7];
  const float* Wm2   = (const float*)d_in[8];
  const float* bm2   = (const float*)d_in[9];
  const float* Wih   = (const float*)d_in[10];
  const float* bih   = (const float*)d_in[11];
  const float* Whh   = (const float*)d_in[12];
  const float* bhh   = (const float*)d_in[13];
  const float* Wh1   = (const float*)d_in[14];
  const float* bh1   = (const float*)d_in[15];
  const float* Wh2   = (const float*)d_in[16];
  const float* bh2   = (const float*)d_in[17];

  char* w = (char*)d_ws;
  float* h     = (float*)w;                      w += (size_t)NN * HD * 4;
  unsigned* h_bf = (unsigned*)w;                 w += (size_t)NN * 32 * 4;
  float* agg   = (float*)w;                      w += (size_t)NN * HD * 4;
  int*   deg   = (int*)w;                        w += (size_t)NN * 4;
  int*   cur   = (int*)w;                        w += (size_t)NN * 4;
  int4*  sde   = (int4*)w;                       w += (size_t)NE * 16;
  int2*  sd8   = (int2*)w;                       w += (size_t)NE * 8;
  int*   bsum  = (int*)w;                        w += 64 * 4;
  int*   bpre  = (int*)w;                        w += 64 * 4;
  unsigned short* W1Tp = (unsigned short*)w;     w += 64 * 168 * 2;
  unsigned short* W2Tp = (unsigned short*)w;     w += 64 * 72 * 2;
  unsigned short* Wgru = (unsigned short*)w;     w += 384 * 64 * 2;
  unsigned short* W1cTp = (unsigned short*)w;    w += 64 * 32 * 2 + 192;   // keep 16B alignment
  float* gsum  = (float*)w;                      w += (size_t)NG * HD * 4;
  float* cnt   = (float*)w;                      w += (size_t)NG * 4;
  unsigned* C12 = (unsigned*)w;                  w += (size_t)NN * 64 * 4;
  unsigned* E1s = (unsigned*)w;                  w += (size_t)NE * 32 * 4;

  const int nscanb = (NN + 1023) / 1024;

  k_prep<<<164, 256, 0, stream>>>(Wm1, Wm2, Wih, Whh, bm1, W1Tp, W2Tp, Wgru, W1cTp);
  hipMemsetAsync(deg, 0, (size_t)NN * 4, stream);
  k_hist<<<HGRID, 256, 0, stream>>>(eidx, deg);
  k_scan1<<<nscanb, 1024, 0, stream>>>(deg, cur, bsum);
  k_scan2<<<1, 64, 0, stream>>>(bsum, bpre);
  k_scan3<<<nscanb, 1024, 0, stream>>>(cur, bpre);
  k_scatter<<<SGRID, 256, 0, stream>>>(eidx, cur, sde);
  k_eprep<<<EPGRID, 256, 0, stream>>>(sde, eattr, (const unsigned*)W1cTp, E1s, sd8);

  k_embed<<<NN / 4, 256, 0, stream>>>(x, We, be, h, h_bf, agg);
  for (int s = 0; s < 3; ++s){
    k_pre<<<PGRID, 256, 0, stream>>>(h_bf, W1Tp, C12);
    k_edge<<<EGRID, 256, 0, stream>>>(C12, E1s, sd8, (const unsigned*)W2Tp, bm2, agg);
    k_gru<<<GGRID, 256, 0, stream>>>(agg, h, h_bf, Wgru, bih, bhh);
  }
  hipMemsetAsync(gsum, 0, (size_t)(NG * HD + NG) * 4, stream);
  k_pool<<<(NN + 63) / 64, 256, 0, stream>>>(h, batch, gsum, cnt);
  k_head<<<NG, 64, 0, stream>>>(gsum, cnt, Wh1, bh1, Wh2, bh2, (float*)d_out);
}

// Round 10
// 568.137 us; speedup vs baseline: 1.0567x; 1.0567x over previous
//
#include <hip/hip_runtime.h>
#include <math.h>

#define NN 50000
#define NE 800000
#define AD 32
#define ED 16
#define HD 64
#define NG 256
#define NTILES (NE / 16)     // 50000 wave-tiles of 16 edges
#define EGRID 1280           // persistent blocks for k_edge
#define TPX (NTILES / 8)     // tiles per XCD chunk
#define GGRID 768            // persistent blocks for k_gru (3 per CU)
#define GTILES (NN / 16)     // 3125 node-tiles
#define PGRID 782            // k_pre blocks
#define SGRID 1024           // k_scatter blocks (8 XCD groups x 128)
#define HGRID 1024           // k_hist blocks
#define NPX (NN / 8)         // 6250 nodes per XCD dst-range

typedef short bf16x8 __attribute__((ext_vector_type(8)));
typedef float f32x4  __attribute__((ext_vector_type(4)));
union U4B { uint4 u; bf16x8 v; };

__device__ __forceinline__ float blo(unsigned u){ return __uint_as_float(u << 16); }
__device__ __forceinline__ float bhi(unsigned u){ return __uint_as_float(u & 0xffff0000u); }
__device__ __forceinline__ unsigned short f2bf(float f){
  unsigned u = __float_as_uint(f);
  u += 0x7fffu + ((u >> 16) & 1u);          // RNE
  return (unsigned short)(u >> 16);
}
__device__ __forceinline__ unsigned packbf2(float a, float b){
  return (unsigned)f2bf(a) | ((unsigned)f2bf(b) << 16);
}
__device__ __forceinline__ bf16x8 ldfrag_g(const unsigned* p){
  U4B x; x.u = *(const uint4*)p; return x.v;
}
// relu(a+b+c) on packed bf16 pairs -> packed bf16
__device__ __forceinline__ unsigned srp1(unsigned a, unsigned b, unsigned c){
  float lo = fmaxf(blo(a) + blo(b) + blo(c), 0.f);
  float hi = fmaxf(bhi(a) + bhi(b) + bhi(c), 0.f);
  return packbf2(lo, hi);
}
__device__ __forceinline__ bf16x8 srp4(uint4 a, uint4 b, uint4 c){
  U4B r;
  r.u.x = srp1(a.x, b.x, c.x);
  r.u.y = srp1(a.y, b.y, c.y);
  r.u.z = srp1(a.z, b.z, c.z);
  r.u.w = srp1(a.w, b.w, c.w);
  return r.v;
}

// =============== one-time prep: weights -> bf16 ===============
__global__ __launch_bounds__(256) void k_prep(const float* __restrict__ W1,
                                              const float* __restrict__ W2,
                                              const float* __restrict__ Wih,
                                              const float* __restrict__ Whh,
                                              const float* __restrict__ b1,
                                              unsigned short* __restrict__ W1Tp,
                                              unsigned short* __restrict__ W2Tp,
                                              unsigned short* __restrict__ Wgru,
                                              unsigned short* __restrict__ W1cTp)
{
  int idx = blockIdx.x * 256 + threadIdx.x;
  if (idx < 64 * 168){
    int n = idx / 168, k = idx % 168;
    W1Tp[idx] = (k < 144) ? f2bf(W1[k * 64 + n]) : (unsigned short)0;
    return;
  }
  idx -= 64 * 168;
  if (idx < 64 * 72){
    int n = idx / 72, k = idx % 72;
    W2Tp[idx] = (k < 64) ? f2bf(W2[k * 64 + n]) : (unsigned short)0;
    return;
  }
  idx -= 64 * 72;
  if (idx < 384 * 64){
    int j = idx & 7;
    int g = (idx >> 3) % 384;
    int blk = idx >> 3; blk /= 384;         // 0..7
    int q = blk & 3, ks = blk >> 2;
    int k = ks * 32 + q * 8 + j;
    float v = (g < 192) ? Wih[g * 64 + k] : Whh[(g - 192) * 64 + k];
    Wgru[idx] = f2bf(v);
    return;
  }
  idx -= 384 * 64;
  if (idx < 64 * 32){
    int n = idx / 32, k = idx % 32;
    float v = (k < 16) ? W1[(128 + k) * 64 + n] : (k == 16 ? b1[n] : 0.f);
    W1cTp[idx] = f2bf(v);
  }
}

// =============== CSR build (XCD-partitioned atomics) ===============
__global__ __launch_bounds__(256) void k_hist(const int* __restrict__ eidx, int* __restrict__ deg)
{
  const int g = blockIdx.x & 7, bi = blockIdx.x >> 3;
  const int lo = g * NPX, hi = lo + NPX;
  for (int e = bi * 256 + threadIdx.x; e < NE; e += (HGRID / 8) * 256){
    int d = eidx[NE + e];
    if (d >= lo && d < hi) atomicAdd(&deg[d], 1);
  }
}

__global__ __launch_bounds__(1024) void k_scan1(const int* __restrict__ deg,
                                                int* __restrict__ cur,
                                                int* __restrict__ bsum)
{
  __shared__ int s[1024];
  const int t = threadIdx.x;
  const int idx = blockIdx.x * 1024 + t;
  int v = (idx < NN) ? deg[idx] : 0;
  s[t] = v;
  __syncthreads();
  for (int d = 1; d < 1024; d <<= 1){
    int y = (t >= d) ? s[t - d] : 0;
    __syncthreads();
    s[t] += y;
    __syncthreads();
  }
  if (idx < NN) cur[idx] = s[t] - v;
  if (t == 1023) bsum[blockIdx.x] = s[1023];
}

__global__ __launch_bounds__(64) void k_scan2(const int* __restrict__ bsum,
                                              int* __restrict__ bpre)
{
  const int t = threadIdx.x;
  const int nb = (NN + 1023) / 1024;
  int v = (t < nb) ? bsum[t] : 0;
  int orig = v;
  #pragma unroll
  for (int off = 1; off < 64; off <<= 1){
    int u = __shfl_up(v, off);
    if (t >= off) v += u;
  }
  if (t < nb) bpre[t] = v - orig;
}

__global__ __launch_bounds__(1024) void k_scan3(int* __restrict__ cur,
                                                const int* __restrict__ bpre)
{
  const int idx = blockIdx.x * 1024 + threadIdx.x;
  if (idx < NN) cur[idx] += bpre[blockIdx.x];
}

// scatter: XCD-partitioned — group g only handles dst in its 1/8 range
__global__ __launch_bounds__(256) void k_scatter(const int* __restrict__ eidx,
                                                 int* __restrict__ cur,
                                                 int4* __restrict__ sde)
{
  const int g = blockIdx.x & 7, bi = blockIdx.x >> 3;
  const int lo = g * NPX, hi = lo + NPX;
  for (int e = bi * 256 + threadIdx.x; e < NE; e += (SGRID / 8) * 256){
    int d = eidx[NE + e];
    if (d >= lo && d < hi){
      int s = eidx[e];
      int p = atomicAdd(&cur[d], 1);
      sde[p] = make_int4(s, d, e, 0);
    }
  }
}

// =============== once: sd8 + eattr_s (bf16, sorted order) ===============
__global__ __launch_bounds__(256) void k_esort(const int4* __restrict__ sde,
                                               const float* __restrict__ eattr,
                                               int2* __restrict__ sd8,
                                               unsigned* __restrict__ eattr_s)
{
  int p = blockIdx.x * 256 + threadIdx.x;
  if (p >= NE) return;
  int4 rec = sde[p];
  sd8[p] = make_int2(rec.x, rec.y);
  const float* ea = eattr + (size_t)rec.z * 16;
  float4 v0 = *(const float4*)(ea);
  float4 v1 = *(const float4*)(ea + 4);
  float4 v2 = *(const float4*)(ea + 8);
  float4 v3 = *(const float4*)(ea + 12);
  uint4 o0, o1;
  o0.x = packbf2(v0.x, v0.y); o0.y = packbf2(v0.z, v0.w);
  o0.z = packbf2(v1.x, v1.y); o0.w = packbf2(v1.z, v1.w);
  o1.x = packbf2(v2.x, v2.y); o1.y = packbf2(v2.z, v2.w);
  o1.z = packbf2(v3.x, v3.y); o1.w = packbf2(v3.z, v3.w);
  *(uint4*)(eattr_s + (size_t)p * 8)     = o0;
  *(uint4*)(eattr_s + (size_t)p * 8 + 4) = o1;
}

// =============== per step: C12[node] = [h@W1a | h@W1b] bf16 ===============
__global__ __launch_bounds__(256, 4) void k_pre(const unsigned* __restrict__ h_bf,
                                                const unsigned short* __restrict__ W1Tp,
                                                unsigned* __restrict__ C12)
{
  const int t = threadIdx.x, lane = t & 63, wv = t >> 6;
  const int m = lane & 15, q = lane >> 4;
  bf16x8 wa[4][2], wb[4][2];
  #pragma unroll
  for (int tl = 0; tl < 4; ++tl)
    #pragma unroll
    for (int ks = 0; ks < 2; ++ks){
      wa[tl][ks] = ldfrag_g((const unsigned*)(W1Tp + (tl * 16 + m) * 168 + ks * 32 + q * 8));
      wb[tl][ks] = ldfrag_g((const unsigned*)(W1Tp + (tl * 16 + m) * 168 + 64 + ks * 32 + q * 8));
    }
  for (int wt = blockIdx.x * 4 + wv; wt < GTILES; wt += PGRID * 4){
    const int n0 = wt * 16;
    bf16x8 aH[2];
    #pragma unroll
    for (int ks = 0; ks < 2; ++ks)
      aH[ks] = ldfrag_g(h_bf + (size_t)(n0 + m) * 32 + ks * 16 + q * 4);
    f32x4 ca[4], cb[4];
    #pragma unroll
    for (int tl = 0; tl < 4; ++tl){ ca[tl] = f32x4{0.f,0.f,0.f,0.f}; cb[tl] = ca[tl]; }
    #pragma unroll
    for (int ks = 0; ks < 2; ++ks)
      #pragma unroll
      for (int tl = 0; tl < 4; ++tl){
        ca[tl] = __builtin_amdgcn_mfma_f32_16x16x32_bf16(aH[ks], wa[tl][ks], ca[tl], 0, 0, 0);
        cb[tl] = __builtin_amdgcn_mfma_f32_16x16x32_bf16(aH[ks], wb[tl][ks], cb[tl], 0, 0, 0);
      }
    #pragma unroll
    for (int tl = 0; tl < 4; ++tl){
      #pragma unroll
      for (int rr = 0; rr < 4; ++rr){
        const int node = n0 + q * 4 + rr;
        float va = ca[tl][rr], vb = cb[tl][rr];
        float pa = __shfl_xor(va, 1), pb = __shfl_xor(vb, 1);
        if (!(m & 1)){
          C12[(size_t)node * 64 + (tl * 16 + m) / 2]      = packbf2(va, pa);
          C12[(size_t)node * 64 + 32 + (tl * 16 + m) / 2] = packbf2(vb, pb);
        }
      }
    }
  }
}

// =============== embed: h + h_bf (+ zero agg) ===============
__global__ __launch_bounds__(256) void k_embed(const float* __restrict__ x,
                                               const float* __restrict__ We,
                                               const float* __restrict__ be,
                                               float* __restrict__ h,
                                               unsigned* __restrict__ h_bf,
                                               float* __restrict__ agg)
{
  const int t = threadIdx.x;
  const int j = t & 63, nd = t >> 6;
  const int node = blockIdx.x * 4 + nd;
  const float* xr = x + (size_t)node * AD;
  float acc = be[j];
  #pragma unroll 8
  for (int k = 0; k < AD; ++k)
    acc += xr[k] * We[k * HD + j];
  h[(size_t)node * HD + j] = acc;
  agg[(size_t)node * HD + j] = 0.f;
  float p = __shfl_down(acc, 1);
  if (!(j & 1)) h_bf[(size_t)node * 32 + (j >> 1)] = packbf2(acc, p);
}

// =============== edge kernel: inline E1 via transposed MFMA + per-wave LDS bounce ===============
__global__ __launch_bounds__(256, 4) void k_edge(const unsigned* __restrict__ C12,
                                                 const unsigned* __restrict__ eattr_s,
                                                 const int2* __restrict__ sd8,
                                                 const unsigned* __restrict__ W2Tp32,
                                                 const unsigned* __restrict__ W1cTp32,
                                                 const float* __restrict__ b2,
                                                 float* __restrict__ agg)
{
  // per-wave E1 bounce: 16 edges x 64 cols bf16, row stride 72 shorts (144 B, 16B-aligned)
  __shared__ __align__(16) unsigned short sE1[4][16 * 72];

  const int t = threadIdx.x;
  const int lane = t & 63, wv = t >> 6;
  const int m = lane & 15, q = lane >> 4;

  bf16x8 w2f[4][2];
  #pragma unroll
  for (int tl = 0; tl < 4; ++tl)
    #pragma unroll
    for (int ks = 0; ks < 2; ++ks)
      w2f[tl][ks] = ldfrag_g(W2Tp32 + (tl * 16 + m) * 36 + ks * 16 + q * 4);

  // W1c col-frags: A-operand of the transposed E1 MFMA (A[m][k] = W1c[k][tl*16+m])
  bf16x8 wf[4];
  #pragma unroll
  for (int tl = 0; tl < 4; ++tl)
    wf[tl] = ldfrag_g(W1cTp32 + (tl * 16 + m) * 16 + q * 4);

  float b2v[4];
  #pragma unroll
  for (int tl = 0; tl < 4; ++tl) b2v[tl] = b2[tl * 16 + m];

  unsigned short* sE1w = sE1[wv];

  const int xcd = blockIdx.x & 7, bi = blockIdx.x >> 3;
  const int wend = (xcd + 1) * TPX;
  const int wstep = (EGRID / 8) * 4;
  int wt = xcd * TPX + bi * 4 + wv;

  int2 cursd = sd8[wt * 16 + m];

  while (wt < wend){
    const int wn = wt + wstep;
    const bool hasn = (wn < wend);
    int2 nsd = make_int2(0, 0);
    if (hasn) nsd = sd8[wn * 16 + m];

    const int scur = cursd.x, dcur = cursd.y;

    // ---- E1^T = W1cT (A) x eattr (B): lane m = edge m, rows = E1 cols ----
    U4B ea;
    if (q < 2)      ea.u = *(const uint4*)(eattr_s + (size_t)(wt * 16 + m) * 8 + q * 4);
    else if (q == 2) ea.u = make_uint4(0x3F80u, 0, 0, 0);   // k=16 -> 1.0 (bias slot)
    else             ea.u = make_uint4(0, 0, 0, 0);
    f32x4 e1t[4];
    #pragma unroll
    for (int tl = 0; tl < 4; ++tl){
      e1t[tl] = f32x4{0.f,0.f,0.f,0.f};
      e1t[tl] = __builtin_amdgcn_mfma_f32_16x16x32_bf16(wf[tl], ea.v, e1t[tl], 0, 0, 0);
    }
    // lane (m,q) holds E1[edge m][col = tl*16 + q*4 + rr] -> LDS (bf16 pairs)
    {
      unsigned* row = (unsigned*)(sE1w + m * 72);
      #pragma unroll
      for (int tl = 0; tl < 4; ++tl){
        row[tl * 8 + q * 2 + 0] = packbf2(e1t[tl][0], e1t[tl][1]);
        row[tl * 8 + q * 2 + 1] = packbf2(e1t[tl][2], e1t[tl][3]);
      }
    }

    // gather operands (C1[src], C2[dst])
    const unsigned* c1p = C12 + (size_t)scur * 64;
    const unsigned* c2p = C12 + (size_t)dcur * 64 + 32;
    uint4 c1a = *(const uint4*)(c1p + q * 4);
    uint4 c1b = *(const uint4*)(c1p + 16 + q * 4);
    uint4 c2a = *(const uint4*)(c2p + q * 4);
    uint4 c2b = *(const uint4*)(c2p + 16 + q * 4);

    // E1 back from LDS in A-frag layout (edge m, cols 8q..8q+7 / 32+8q..)
    uint4 e1a = *(const uint4*)(sE1w + m * 72 + q * 8);
    uint4 e1b = *(const uint4*)(sE1w + m * 72 + 32 + q * 8);

    // hidden = relu(C1+C2+E1) -> bf16 A-frags
    bf16x8 af0 = srp4(c1a, c2a, e1a);
    bf16x8 af1 = srp4(c1b, c2b, e1b);

    // GEMM2: out = hidden @ W2
    f32x4 o0 = {0.f,0.f,0.f,0.f}, o1 = o0, o2 = o0, o3 = o0;
    o0 = __builtin_amdgcn_mfma_f32_16x16x32_bf16(af0, w2f[0][0], o0, 0, 0, 0);
    o1 = __builtin_amdgcn_mfma_f32_16x16x32_bf16(af0, w2f[1][0], o1, 0, 0, 0);
    o2 = __builtin_amdgcn_mfma_f32_16x16x32_bf16(af0, w2f[2][0], o2, 0, 0, 0);
    o3 = __builtin_amdgcn_mfma_f32_16x16x32_bf16(af0, w2f[3][0], o3, 0, 0, 0);
    o0 = __builtin_amdgcn_mfma_f32_16x16x32_bf16(af1, w2f[0][1], o0, 0, 0, 0);
    o1 = __builtin_amdgcn_mfma_f32_16x16x32_bf16(af1, w2f[1][1], o1, 0, 0, 0);
    o2 = __builtin_amdgcn_mfma_f32_16x16x32_bf16(af1, w2f[2][1], o2, 0, 0, 0);
    o3 = __builtin_amdgcn_mfma_f32_16x16x32_bf16(af1, w2f[3][1], o3, 0, 0, 0);

    // segment reduce from C-frags (row=edge q*4+rr, col=tl*16+m)
    int prev = __shfl_up(dcur, 1);
    bool isStart = (m == 0) || (dcur != prev);
    unsigned long long bal = __ballot(isStart);
    unsigned bs = (unsigned)bal & 0xFFFFu;
    int nr = __popc(bs);
    unsigned rem = bs & (bs - 1);
    int lo = 0;
    for (int r = 0; r < nr; ++r){
      int hi = rem ? (__ffs(rem) - 1) : 16;
      rem &= rem - 1;
      float s0 = 0.f, s1 = 0.f, s2 = 0.f, s3 = 0.f;
      #pragma unroll
      for (int rr = 0; rr < 4; ++rr){
        int row = q * 4 + rr;
        bool in = (row >= lo) && (row < hi);
        s0 += in ? o0[rr] : 0.f;
        s1 += in ? o1[rr] : 0.f;
        s2 += in ? o2[rr] : 0.f;
        s3 += in ? o3[rr] : 0.f;
      }
      s0 += __shfl_xor(s0, 16); s0 += __shfl_xor(s0, 32);
      s1 += __shfl_xor(s1, 16); s1 += __shfl_xor(s1, 32);
      s2 += __shfl_xor(s2, 16); s2 += __shfl_xor(s2, 32);
      s3 += __shfl_xor(s3, 16); s3 += __shfl_xor(s3, 32);
      int d = __shfl(dcur, lo);
      float cntf = (float)(hi - lo);
      if (q == 0){
        float v0 = s0 + cntf * b2v[0];
        float v1 = s1 + cntf * b2v[1];
        float v2 = s2 + cntf * b2v[2];
        float v3 = s3 + cntf * b2v[3];
        float* dp = &agg[(size_t)d * HD + m];
        if (r == 0 || r == nr - 1){
          atomicAdd(dp +  0, v0); atomicAdd(dp + 16, v1);
          atomicAdd(dp + 32, v2); atomicAdd(dp + 48, v3);
        } else {
          dp[ 0] = v0; dp[16] = v1; dp[32] = v2; dp[48] = v3;
        }
      }
      lo = hi;
    }

    wt = wn; cursd = nsd;
  }
}

// =============== GRU via MFMA (zeroes agg after consuming it) ===============
__global__ __launch_bounds__(256) void k_gru(float* __restrict__ agg,
                                             float* __restrict__ h,
                                             unsigned* __restrict__ h_bf,
                                             const unsigned short* __restrict__ Wgru,
                                             const float* __restrict__ bih,
                                             const float* __restrict__ bhh)
{
  __shared__ __align__(16) unsigned short sWg[384 * 64];   // 48 KB

  const int t = threadIdx.x;
  {
    const uint4* srcp = (const uint4*)Wgru;
    uint4* dstp = (uint4*)sWg;
    for (int i = t; i < 384 * 64 * 2 / 16; i += 256) dstp[i] = srcp[i];
  }
  __syncthreads();

  const int lane = t & 63, wv = t >> 6;
  const int m = lane & 15, q = lane >> 4;

  float bi_r[4], bi_z[4], bi_n[4], bh_r[4], bh_z[4], bh_n[4];
  #pragma unroll
  for (int tl = 0; tl < 4; ++tl){
    bi_r[tl] = bih[tl * 16 + m];  bi_z[tl] = bih[64 + tl * 16 + m];  bi_n[tl] = bih[128 + tl * 16 + m];
    bh_r[tl] = bhh[tl * 16 + m];  bh_z[tl] = bhh[64 + tl * 16 + m];  bh_n[tl] = bhh[128 + tl * 16 + m];
  }

  for (int wt = blockIdx.x * 4 + wv; wt < GTILES; wt += GGRID * 4){
    const int n0 = wt * 16;

    bf16x8 aA[2], aH[2];
    #pragma unroll
    for (int ks = 0; ks < 2; ++ks){
      const float* ap = agg + (size_t)(n0 + m) * 64 + ks * 32 + q * 8;
      float4 v0 = *(const float4*)ap;
      float4 v1 = *(const float4*)(ap + 4);
      U4B x;
      x.u.x = packbf2(v0.x, v0.y); x.u.y = packbf2(v0.z, v0.w);
      x.u.z = packbf2(v1.x, v1.y); x.u.w = packbf2(v1.z, v1.w);
      aA[ks] = x.v;
      aH[ks] = ldfrag_g(h_bf + (size_t)(n0 + m) * 32 + ks * 16 + q * 4);
    }

    f32x4 ci[12], ch[12];
    #pragma unroll
    for (int tl = 0; tl < 12; ++tl){ ci[tl] = f32x4{0.f,0.f,0.f,0.f}; ch[tl] = ci[tl]; }
    #pragma unroll
    for (int ks = 0; ks < 2; ++ks){
      #pragma unroll
      for (int tl = 0; tl < 12; ++tl){
        bf16x8 bi = *(const bf16x8*)&sWg[((ks * 4 + q) * 384 + tl * 16 + m) * 8];
        ci[tl] = __builtin_amdgcn_mfma_f32_16x16x32_bf16(aA[ks], bi, ci[tl], 0, 0, 0);
        bf16x8 bh = *(const bf16x8*)&sWg[((ks * 4 + q) * 384 + 192 + tl * 16 + m) * 8];
        ch[tl] = __builtin_amdgcn_mfma_f32_16x16x32_bf16(aH[ks], bh, ch[tl], 0, 0, 0);
      }
    }

    #pragma unroll
    for (int tl = 0; tl < 4; ++tl){
      #pragma unroll
      for (int rr = 0; rr < 4; ++rr){
        const int node = n0 + q * 4 + rr;
        float ir = ci[tl][rr]     + bi_r[tl], hr = ch[tl][rr]     + bh_r[tl];
        float iz = ci[4 + tl][rr] + bi_z[tl], hz = ch[4 + tl][rr] + bh_z[tl];
        float in_ = ci[8 + tl][rr] + bi_n[tl], hn = ch[8 + tl][rr] + bh_n[tl];
        float rg = 1.f / (1.f + __expf(-(ir + hr)));
        float zg = 1.f / (1.f + __expf(-(iz + hz)));
        float ng = tanhf(in_ + rg * hn);
        float hold = h[(size_t)node * HD + tl * 16 + m];
        float hnew = (1.f - zg) * ng + zg * hold;
        h[(size_t)node * HD + tl * 16 + m] = hnew;
        agg[(size_t)node * HD + tl * 16 + m] = 0.f;   // re-zero for next step
        float pp = __shfl_xor(hnew, 1);
        if (!(m & 1))
          h_bf[(size_t)node * 32 + tl * 8 + (m >> 1)] = packbf2(hnew, pp);
      }
    }
  }
}

// =============== pool ===============
__global__ __launch_bounds__(256) void k_pool(const float* __restrict__ h,
                                              const int* __restrict__ batch,
                                              float* __restrict__ gsum,
                                              float* __restrict__ cnt)
{
  const int t = threadIdx.x;
  const int j = t & 63, r = t >> 6;
  const int n0 = blockIdx.x * 64 + r * 16;
  float acc = 0.f, c = 0.f;
  int cur = -1;
  for (int i = 0; i < 16; ++i){
    int n = n0 + i;
    if (n >= NN) break;
    int g = batch[n];
    if (g != cur){
      if (cur >= 0){
        atomicAdd(&gsum[cur * HD + j], acc);
        if (j == 0) atomicAdd(&cnt[cur], c);
      }
      cur = g; acc = 0.f; c = 0.f;
    }
    acc += h[(size_t)n * HD + j];
    c += 1.f;
  }
  if (cur >= 0){
    atomicAdd(&gsum[cur * HD + j], acc);
    if (j == 0) atomicAdd(&cnt[cur], c);
  }
}

// =============== head ===============
__global__ __launch_bounds__(64) void k_head(const float* __restrict__ gsum,
                                             const float* __restrict__ cnt,
                                             const float* __restrict__ W1,
                                             const float* __restrict__ b1,
                                             const float* __restrict__ W2,
                                             const float* __restrict__ b2,
                                             float* __restrict__ out)
{
  __shared__ float gv[128];
  const int g = blockIdx.x, j = threadIdx.x;
  float s = gsum[g * HD + j];
  float c = cnt[g];
  gv[j] = s;
  gv[64 + j] = s / fmaxf(c, 1.f);
  __syncthreads();
  float acc = b1[j];
  #pragma unroll 8
  for (int k = 0; k < 128; ++k)
    acc += gv[k] * W1[k * HD + j];
  acc = fmaxf(acc, 0.f);
  float v = acc * W2[j];
  #pragma unroll
  for (int off = 32; off; off >>= 1) v += __shfl_down(v, off, 64);
  if (j == 0) out[g] = v + b2[0];
}

extern "C" void kernel_launch(void* const* d_in, const int* in_sizes, int n_in,
                              void* d_out, int out_size, void* d_ws, size_t ws_size,
                              hipStream_t stream)
{
  (void)in_sizes; (void)n_in; (void)out_size; (void)ws_size;
  const float* x     = (const float*)d_in[0];
  const int*   eidx  = (const int*)d_in[1];
  const float* eattr = (const float*)d_in[2];
  const int*   batch = (const int*)d_in[3];
  const float* We    = (const float*)d_in[4];
  const float* be    = (const float*)d_in[5];
  const float* Wm1   = (const float*)d_in[6];
  const float* bm1   = (const float*)d_in[7];
  const float* Wm2   = (const float*)d_in[8];
  const float* bm2   = (const float*)d_in[9];
  const float* Wih   = (const float*)d_in[10];
  const float* bih   = (const float*)d_in[11];
  const float* Whh   = (const float*)d_in[12];
  const float* bhh   = (const float*)d_in[13];
  const float* Wh1   = (const float*)d_in[14];
  const float* bh1   = (const float*)d_in[15];
  const float* Wh2   = (const float*)d_in[16];
  const float* bh2   = (const float*)d_in[17];

  char* w = (char*)d_ws;
  float* h     = (float*)w;                      w += (size_t)NN * HD * 4;
  unsigned* h_bf = (unsigned*)w;                 w += (size_t)NN * 32 * 4;
  float* agg   = (float*)w;                      w += (size_t)NN * HD * 4;
  int*   deg   = (int*)w;                        w += (size_t)NN * 4;
  int*   cur   = (int*)w;                        w += (size_t)NN * 4;
  int4*  sde   = (int4*)w;                       w += (size_t)NE * 16;
  int2*  sd8   = (int2*)w;                       w += (size_t)NE * 8;
  unsigned* eattr_s = (unsigned*)w;              w += (size_t)NE * 8 * 4;
  int*   bsum  = (int*)w;                        w += 64 * 4;
  int*   bpre  = (int*)w;                        w += 64 * 4;
  unsigned short* W1Tp = (unsigned short*)w;     w += 64 * 168 * 2;
  unsigned short* W2Tp = (unsigned short*)w;     w += 64 * 72 * 2;
  unsigned short* Wgru = (unsigned short*)w;     w += 384 * 64 * 2;
  unsigned short* W1cTp = (unsigned short*)w;    w += 64 * 32 * 2 + 192;   // keep 16B alignment
  float* gsum  = (float*)w;                      w += (size_t)NG * HD * 4;
  float* cnt   = (float*)w;                      w += (size_t)NG * 4;
  unsigned* C12 = (unsigned*)w;                  w += (size_t)NN * 64 * 4;

  const int nscanb = (NN + 1023) / 1024;

  k_prep<<<164, 256, 0, stream>>>(Wm1, Wm2, Wih, Whh, bm1, W1Tp, W2Tp, Wgru, W1cTp);
  hipMemsetAsync(deg, 0, (size_t)NN * 4, stream);
  k_hist<<<HGRID, 256, 0, stream>>>(eidx, deg);
  k_scan1<<<nscanb, 1024, 0, stream>>>(deg, cur, bsum);
  k_scan2<<<1, 64, 0, stream>>>(bsum, bpre);
  k_scan3<<<nscanb, 1024, 0, stream>>>(cur, bpre);
  k_scatter<<<SGRID, 256, 0, stream>>>(eidx, cur, sde);
  k_esort<<<(NE + 255) / 256, 256, 0, stream>>>(sde, eattr, sd8, eattr_s);

  k_embed<<<NN / 4, 256, 0, stream>>>(x, We, be, h, h_bf, agg);
  for (int s = 0; s < 3; ++s){
    k_pre<<<PGRID, 256, 0, stream>>>(h_bf, W1Tp, C12);
    k_edge<<<EGRID, 256, 0, stream>>>(C12, eattr_s, sd8, (const unsigned*)W2Tp,
                                      (const unsigned*)W1cTp, bm2, agg);
    k_gru<<<GGRID, 256, 0, stream>>>(agg, h, h_bf, Wgru, bih, bhh);
  }
  hipMemsetAsync(gsum, 0, (size_t)(NG * HD + NG) * 4, stream);
  k_pool<<<(NN + 63) / 64, 256, 0, stream>>>(h, batch, gsum, cnt);
  k_head<<<NG, 64, 0, stream>>>(gsum, cnt, Wh1, bh1, Wh2, bh2, (float*)d_out);
}